// Round 5
// baseline (41422.318 us; speedup 1.0000x reference)
//
#include <hip/hip_runtime.h>
#include <hip/hip_cooperative_groups.h>
#include <stdint.h>
#include <math.h>

// ---------------------------------------------------------------------------
// QuantumDiffusionDreamer — round 15: MEGA-FUSION. r13 measured 8060 µs with
// ~161 µs/step while best-case kernel sum is ~100 µs/step; two consecutive
// GEMM-structure ports moved <1% => the residual is inter-dispatch overhead
// (250 dependent launch boundaries). This round fuses the whole 50-step loop
// into ONE cooperative kernel (grid 256 = 1 block/CU, 128 KiB LDS), with
// __threadfence()+grid.sync() between stages:
//   G1 (128x256 8ph) -> G2 (256^2 8ph) -> G45 (128x256 8ph z-pair)
//   -> G6 (128x256 8ph A-split) -> G7 (128x128 2ph + fused DDPM epilogue)
// G7 re-tiled 64x128->128x128 for the 256-block grid (r9-proven core); PRNG
// 32 normals/thread at 8 waves/CU (same VALU work/CU as r10's 16@16).
// Per-step scalars computed in-kernel bit-identically (same double->float
// exprs, integer threefry); decay as literal (<=1 ulp on qi, harmless).
// Transposes + init + final unchanged as separate dispatches.
// ---------------------------------------------------------------------------

namespace cg = cooperative_groups;

typedef __bf16 bf16x8 __attribute__((ext_vector_type(8)));
typedef float floatx4 __attribute__((ext_vector_type(4)));

__host__ __device__ inline void tf2x32(uint32_t k0, uint32_t k1,
                                       uint32_t x0, uint32_t x1,
                                       uint32_t& o0, uint32_t& o1) {
  uint32_t ks2 = k0 ^ k1 ^ 0x1BD11BDAu;
#define TF_R(r) { x0 += x1; x1 = (x1 << (r)) | (x1 >> (32 - (r))); x1 ^= x0; }
  x0 += k0; x1 += k1;
  TF_R(13) TF_R(15) TF_R(26) TF_R(6)
  x0 += k1;  x1 += ks2 + 1u;
  TF_R(17) TF_R(29) TF_R(16) TF_R(24)
  x0 += ks2; x1 += k0 + 2u;
  TF_R(13) TF_R(15) TF_R(26) TF_R(6)
  x0 += k0;  x1 += k1 + 3u;
  TF_R(17) TF_R(29) TF_R(16) TF_R(24)
  x0 += k1;  x1 += ks2 + 4u;
  TF_R(13) TF_R(15) TF_R(26) TF_R(6)
  x0 += ks2; x1 += k0 + 5u;
#undef TF_R
  o0 = x0; o1 = x1;
}

__device__ inline float erfinv_f32(float x) {
  float w = -log1pf(-x * x);
  float p;
  if (w < 5.0f) {
    w = w - 2.5f;
    p = 2.81022636e-08f;
    p = fmaf(p, w, 3.43273939e-07f);
    p = fmaf(p, w, -3.5233877e-06f);
    p = fmaf(p, w, -4.39150654e-06f);
    p = fmaf(p, w, 0.00021858087f);
    p = fmaf(p, w, -0.00125372503f);
    p = fmaf(p, w, -0.00417768164f);
    p = fmaf(p, w, 0.246640727f);
    p = fmaf(p, w, 1.50140941f);
  } else {
    w = sqrtf(w) - 3.0f;
    p = -0.000200214257f;
    p = fmaf(p, w, 0.000100950558f);
    p = fmaf(p, w, 0.00134934322f);
    p = fmaf(p, w, -0.00367342844f);
    p = fmaf(p, w, 0.00573950773f);
    p = fmaf(p, w, -0.0076224613f);
    p = fmaf(p, w, 0.00943887047f);
    p = fmaf(p, w, 1.00167406f);
    p = fmaf(p, w, 2.83297682f);
  }
  return p * x;
}

__device__ inline float tf_normal(uint32_t k0, uint32_t k1, uint32_t i) {
  uint32_t o0, o1;
  tf2x32(k0, k1, 0u, i, o0, o1);
  uint32_t bits = o0 ^ o1;  // partitionable random_bits path
  float f = __uint_as_float(0x3F800000u | (bits >> 9)) - 1.0f;  // [0,1)
  float u = f * 2.0f + (-0.99999994f);
  u = fmaxf(-0.99999994f, u);
  return 1.41421356f * erfinv_f32(u);
}

__device__ inline unsigned short f2bf(float f) {
  uint32_t u = __float_as_uint(f);
  u += 0x7FFFu + ((u >> 16) & 1u);   // round-to-nearest-even
  return (unsigned short)(u >> 16);
}
__device__ inline float bf2f(unsigned short h) {
  return __uint_as_float(((uint32_t)h) << 16);
}

__device__ __forceinline__ void gload16(const unsigned short* g,
                                        unsigned short* l) {
  __builtin_amdgcn_global_load_lds(
      (const __attribute__((address_space(1))) uint32_t*)g,
      (__attribute__((address_space(3))) uint32_t*)l, 16, 0, 0);
}

// ---------------------------------------------------------------------------
// Weight transpose + bf16 convert: Wt[n][k] = bf16(W[k][n]);  W is [K,N] fp32.
// ---------------------------------------------------------------------------
__global__ __launch_bounds__(256)
void transpose_bf16_kernel(const float* __restrict__ W,
                           unsigned short* __restrict__ Wt, int K, int N) {
  __shared__ float tile[32][33];
  int kb = blockIdx.x * 32, nb = blockIdx.y * 32;
  int tx = threadIdx.x & 31, ty = threadIdx.x >> 5;
#pragma unroll
  for (int i = 0; i < 32; i += 8)
    tile[ty + i][tx] = W[(size_t)(kb + ty + i) * N + nb + tx];
  __syncthreads();
#pragma unroll
  for (int i = 0; i < 32; i += 8)
    Wt[(size_t)(nb + ty + i) * K + kb + tx] = f2bf(tile[tx][ty + i]);
}

// ---------------------------------------------------------------------------
// 8-phase MFMA phase helpers (T5 setprio; rule-18 sched_barrier).
// ---------------------------------------------------------------------------
template<int MH, int NH>
__device__ __forceinline__ void phase_mfma8(bf16x8 (&a)[4][2], bf16x8 (&b)[4][2],
                                            floatx4 (&acc)[8][4]) {
  asm volatile("s_waitcnt lgkmcnt(0)" ::: "memory");
  __builtin_amdgcn_sched_barrier(0);
  __builtin_amdgcn_s_setprio(1);
#pragma unroll
  for (int s = 0; s < 2; s++)
#pragma unroll
    for (int mm = 0; mm < 4; mm++)
#pragma unroll
      for (int nn = 0; nn < 2; nn++)
        acc[MH * 4 + mm][NH * 2 + nn] = __builtin_amdgcn_mfma_f32_16x16x32_bf16(
            a[mm][s], b[NH * 2 + nn][s], acc[MH * 4 + mm][NH * 2 + nn], 0, 0, 0);
  __builtin_amdgcn_s_setprio(0);
}

template<int MH, int NH>
__device__ __forceinline__ void phase_mfma4(bf16x8 (&a)[4][2], bf16x8 (&b)[4][2],
                                            floatx4 (&acc)[4][4]) {
  asm volatile("s_waitcnt lgkmcnt(0)" ::: "memory");
  __builtin_amdgcn_sched_barrier(0);
  __builtin_amdgcn_s_setprio(1);
#pragma unroll
  for (int s = 0; s < 2; s++)
#pragma unroll
    for (int mm = 0; mm < 2; mm++)
#pragma unroll
      for (int nn = 0; nn < 2; nn++)
        acc[MH * 2 + mm][NH * 2 + nn] = __builtin_amdgcn_mfma_f32_16x16x32_bf16(
            a[MH * 2 + mm][s], b[NH * 2 + nn][s], acc[MH * 2 + mm][NH * 2 + nn],
            0, 0, 0);
  __builtin_amdgcn_s_setprio(0);
}

// ---------------------------------------------------------------------------
// Stage: 128x256-tile 8-phase GEMM (G1/G45/G6). LDS: As [2][8192] @lds,
// Bs [2][16384] @lds+16384 (96 KiB). 256 blocks, XCD-chunked.
// ---------------------------------------------------------------------------
template<int ACT, int PAIR>
__device__ __forceinline__ void stage_128x256(
    const unsigned short* A0, const unsigned short* A1,
    int lda0, int lda1, int K0, int Ktot,
    const unsigned short* Bt, const float* bias,
    unsigned short* C, int ldc,
    const unsigned short* Ab, const unsigned short* Btb,
    const float* biasb, unsigned short* Cb,
    unsigned short* lds) {
  unsigned short* As = lds;            // [2][8192]
  unsigned short* Bs = lds + 16384;    // [2][16384]
  const int tid = threadIdx.x;
  const int wave = tid >> 6, lane = tid & 63;
  const int wr = wave >> 2, wc = wave & 3;     // 64-row band / 64-col band
  const int fm = lane & 15, quad = lane >> 4;
  const int id = blockIdx.x;
  const int nid = (id & 7) * 32 + (id >> 3);   // XCD-chunked (256 blocks)
  int row0, col0;
  if (PAIR) {
    const int rem = nid & 127;
    row0 = (rem & 63) << 7;
    col0 = (rem >> 6) << 8;
    if (nid >> 7) { A0 = Ab; A1 = Ab; Bt = Btb; bias = biasb; C = Cb; }
  } else {
    row0 = (nid & 63) << 7;
    col0 = (nid >> 6) << 8;
  }
  const int NKT = Ktot >> 6;

  auto stageA = [&](int tile, int buf, int h) {
    if (tile >= NKT) return;
    const int kk = tile << 6;
    const unsigned short* Ap; int kOff, lda;
    if (kk < K0) { Ap = A0; kOff = kk; lda = lda0; }
    else         { Ap = A1; kOff = kk - K0; lda = lda1; }
    const int sr = tid >> 3, gc = tid & 7;
    gload16(Ap + (size_t)(row0 + h * 64 + sr) * lda + kOff + ((gc ^ (sr & 7)) << 3),
            As + buf * 8192 + h * 4096 + tid * 8);
  };
  auto stageB = [&](int tile, int buf, int h) {
    if (tile >= NKT) return;
    const int kk = tile << 6;
#pragma unroll
    for (int c = 0; c < 2; c++) {
      int g2 = c * 512 + tid;
      int sr = g2 >> 3, gc = g2 & 7;
      gload16(Bt + (size_t)(col0 + h * 128 + sr) * Ktot + kk + ((gc ^ (sr & 7)) << 3),
              Bs + buf * 16384 + h * 8192 + g2 * 8);
    }
  };

  const int aswz = (fm & 7) << 3;
  auto rdA = [&](int buf, int m, int s) {
    return *(const bf16x8*)(&As[buf * 8192 + (wr * 64 + m * 16 + fm) * 64 +
                                ((s * 32 + quad * 8) ^ aswz)]);
  };
  auto rdB = [&](int buf, int n, int s) {
    return *(const bf16x8*)(&Bs[buf * 16384 + (wc * 64 + n * 16 + fm) * 64 +
                                ((s * 32 + quad * 8) ^ aswz)]);
  };

  floatx4 acc[4][4];
#pragma unroll
  for (int m = 0; m < 4; m++)
#pragma unroll
    for (int n = 0; n < 4; n++) acc[m][n] = (floatx4){0.f, 0.f, 0.f, 0.f};

  stageA(0, 0, 0); stageA(0, 0, 1);
  stageB(0, 0, 0); stageB(0, 0, 1);
  stageB(1, 1, 0); stageB(1, 1, 1);
  asm volatile("s_waitcnt vmcnt(4)" ::: "memory");
  asm volatile("s_barrier" ::: "memory");

  const int NJ = NKT >> 1;
#pragma unroll 1
  for (int j = 0; j < NJ; j++) {
    const int t1 = 2 * j + 1;
    bf16x8 a[4][2], b[4][2];
    // ---- K-tile 2j (buf 0) ----
#pragma unroll
    for (int mm = 0; mm < 2; mm++) { a[mm][0] = rdA(0, mm, 0); a[mm][1] = rdA(0, mm, 1); }
#pragma unroll
    for (int nn = 0; nn < 2; nn++) { b[nn][0] = rdB(0, nn, 0); b[nn][1] = rdB(0, nn, 1); }
    stageA(t1, 1, 0);
    asm volatile("s_barrier" ::: "memory");
    phase_mfma4<0, 0>(a, b, acc);
    asm volatile("s_barrier" ::: "memory");
#pragma unroll
    for (int nn = 2; nn < 4; nn++) { b[nn][0] = rdB(0, nn, 0); b[nn][1] = rdB(0, nn, 1); }
    stageA(t1, 1, 1);
    asm volatile("s_barrier" ::: "memory");
    phase_mfma4<0, 1>(a, b, acc);
    asm volatile("s_barrier" ::: "memory");
#pragma unroll
    for (int mm = 2; mm < 4; mm++) { a[mm][0] = rdA(0, mm, 0); a[mm][1] = rdA(0, mm, 1); }
    stageB(t1 + 1, 0, 0);
    asm volatile("s_barrier" ::: "memory");
    phase_mfma4<1, 1>(a, b, acc);
    asm volatile("s_barrier" ::: "memory");
    stageB(t1 + 1, 0, 1);
    asm volatile("s_barrier" ::: "memory");
    phase_mfma4<1, 0>(a, b, acc);
    if (j == NJ - 1) asm volatile("s_waitcnt vmcnt(0)" ::: "memory");
    else             asm volatile("s_waitcnt vmcnt(4)" ::: "memory");
    asm volatile("s_barrier" ::: "memory");
    // ---- K-tile 2j+1 (buf 1) ----
#pragma unroll
    for (int mm = 0; mm < 2; mm++) { a[mm][0] = rdA(1, mm, 0); a[mm][1] = rdA(1, mm, 1); }
#pragma unroll
    for (int nn = 0; nn < 2; nn++) { b[nn][0] = rdB(1, nn, 0); b[nn][1] = rdB(1, nn, 1); }
    stageA(t1 + 1, 0, 0);
    asm volatile("s_barrier" ::: "memory");
    phase_mfma4<0, 0>(a, b, acc);
    asm volatile("s_barrier" ::: "memory");
#pragma unroll
    for (int nn = 2; nn < 4; nn++) { b[nn][0] = rdB(1, nn, 0); b[nn][1] = rdB(1, nn, 1); }
    stageA(t1 + 1, 0, 1);
    asm volatile("s_barrier" ::: "memory");
    phase_mfma4<0, 1>(a, b, acc);
    asm volatile("s_barrier" ::: "memory");
#pragma unroll
    for (int mm = 2; mm < 4; mm++) { a[mm][0] = rdA(1, mm, 0); a[mm][1] = rdA(1, mm, 1); }
    stageB(t1 + 2, 1, 0);
    asm volatile("s_barrier" ::: "memory");
    phase_mfma4<1, 1>(a, b, acc);
    asm volatile("s_barrier" ::: "memory");
    stageB(t1 + 2, 1, 1);
    asm volatile("s_barrier" ::: "memory");
    phase_mfma4<1, 0>(a, b, acc);
    asm volatile("s_waitcnt vmcnt(4)" ::: "memory");
    asm volatile("s_barrier" ::: "memory");
  }

#pragma unroll
  for (int n = 0; n < 4; n++) {
    int col = col0 + wc * 64 + n * 16 + fm;
    float bv = bias[col];
#pragma unroll
    for (int m = 0; m < 4; m++) {
      int rbase = row0 + wr * 64 + m * 16 + quad * 4;
#pragma unroll
      for (int r = 0; r < 4; r++) {
        float val = acc[m][n][r] + bv;
        if (ACT == 1) val = fmaxf(val, 0.0f);
        if (ACT == 3) val = 0.5f * val * (1.0f + erff(val * 0.70710678118654752f));
        C[(size_t)(rbase + r) * ldc + col] = f2bf(val);
      }
    }
  }
}

// ---------------------------------------------------------------------------
// Stage: G2 256x256-tile 8-phase (r12 hardware-verified). LDS: As [2][16384]
// @lds, Bs [2][16384] @lds+32768 (128 KiB).
// ---------------------------------------------------------------------------
__device__ __forceinline__ void stage_g2(
    const unsigned short* A, const unsigned short* Bt,
    const float* bias0, const float* bias1,
    unsigned short* C0, unsigned short* C1, unsigned short* lds) {
  constexpr int NKT = 16;
  unsigned short* As = lds;            // [2][16384]
  unsigned short* Bs = lds + 32768;    // [2][16384]
  const int tid = threadIdx.x;
  const int wave = tid >> 6, lane = tid & 63;
  const int wr = wave >> 2, wc = wave & 3;
  const int fm = lane & 15, quad = lane >> 4;
  const int id = blockIdx.x;
  const int nid = (id & 7) * 32 + (id >> 3);
  const int row0 = (nid & 31) << 8;
  const int col0 = (nid >> 5) << 8;

  auto stageA = [&](int tile, int buf, int h) {
    if (tile >= NKT) return;
    const int kk = tile << 6;
#pragma unroll
    for (int c = 0; c < 2; c++) {
      int g2 = c * 512 + tid;
      int sr = g2 >> 3, gc = g2 & 7;
      gload16(A + (size_t)(row0 + h * 128 + sr) * 1024 + kk + ((gc ^ (sr & 7)) << 3),
              As + buf * 16384 + h * 8192 + g2 * 8);
    }
  };
  auto stageB = [&](int tile, int buf, int h) {
    if (tile >= NKT) return;
    const int kk = tile << 6;
#pragma unroll
    for (int c = 0; c < 2; c++) {
      int g2 = c * 512 + tid;
      int sr = g2 >> 3, gc = g2 & 7;
      gload16(Bt + (size_t)(col0 + h * 128 + sr) * 1024 + kk + ((gc ^ (sr & 7)) << 3),
              Bs + buf * 16384 + h * 8192 + g2 * 8);
    }
  };

  const int aswz = (fm & 7) << 3;
  auto rdA = [&](int buf, int m, int s) {
    return *(const bf16x8*)(&As[buf * 16384 + (wr * 128 + m * 16 + fm) * 64 +
                                ((s * 32 + quad * 8) ^ aswz)]);
  };
  auto rdB = [&](int buf, int n, int s) {
    return *(const bf16x8*)(&Bs[buf * 16384 + (wc * 64 + n * 16 + fm) * 64 +
                                ((s * 32 + quad * 8) ^ aswz)]);
  };

  floatx4 acc[8][4];
#pragma unroll
  for (int m = 0; m < 8; m++)
#pragma unroll
    for (int n = 0; n < 4; n++) acc[m][n] = (floatx4){0.f, 0.f, 0.f, 0.f};

  stageA(0, 0, 0); stageA(0, 0, 1);
  stageB(0, 0, 0); stageB(0, 0, 1);
  stageB(1, 1, 0); stageB(1, 1, 1);
  asm volatile("s_waitcnt vmcnt(4)" ::: "memory");
  asm volatile("s_barrier" ::: "memory");

#pragma unroll 1
  for (int j = 0; j < 8; j++) {
    const int t1 = 2 * j + 1;
    bf16x8 a[4][2], b[4][2];
#pragma unroll
    for (int mm = 0; mm < 4; mm++) { a[mm][0] = rdA(0, mm, 0); a[mm][1] = rdA(0, mm, 1); }
#pragma unroll
    for (int nn = 0; nn < 2; nn++) { b[nn][0] = rdB(0, nn, 0); b[nn][1] = rdB(0, nn, 1); }
    stageA(t1, 1, 0);
    asm volatile("s_barrier" ::: "memory");
    phase_mfma8<0, 0>(a, b, acc);
    asm volatile("s_barrier" ::: "memory");
#pragma unroll
    for (int nn = 2; nn < 4; nn++) { b[nn][0] = rdB(0, nn, 0); b[nn][1] = rdB(0, nn, 1); }
    stageA(t1, 1, 1);
    asm volatile("s_barrier" ::: "memory");
    phase_mfma8<0, 1>(a, b, acc);
    asm volatile("s_barrier" ::: "memory");
#pragma unroll
    for (int mm = 0; mm < 4; mm++) { a[mm][0] = rdA(0, 4 + mm, 0); a[mm][1] = rdA(0, 4 + mm, 1); }
    stageB(t1 + 1, 0, 0);
    asm volatile("s_barrier" ::: "memory");
    phase_mfma8<1, 1>(a, b, acc);
    asm volatile("s_barrier" ::: "memory");
    stageB(t1 + 1, 0, 1);
    asm volatile("s_barrier" ::: "memory");
    phase_mfma8<1, 0>(a, b, acc);
    if (j == 7) asm volatile("s_waitcnt vmcnt(0)" ::: "memory");
    else        asm volatile("s_waitcnt vmcnt(4)" ::: "memory");
    asm volatile("s_barrier" ::: "memory");
#pragma unroll
    for (int mm = 0; mm < 4; mm++) { a[mm][0] = rdA(1, mm, 0); a[mm][1] = rdA(1, mm, 1); }
#pragma unroll
    for (int nn = 0; nn < 2; nn++) { b[nn][0] = rdB(1, nn, 0); b[nn][1] = rdB(1, nn, 1); }
    stageA(t1 + 1, 0, 0);
    asm volatile("s_barrier" ::: "memory");
    phase_mfma8<0, 0>(a, b, acc);
    asm volatile("s_barrier" ::: "memory");
#pragma unroll
    for (int nn = 2; nn < 4; nn++) { b[nn][0] = rdB(1, nn, 0); b[nn][1] = rdB(1, nn, 1); }
    stageA(t1 + 1, 0, 1);
    asm volatile("s_barrier" ::: "memory");
    phase_mfma8<0, 1>(a, b, acc);
    asm volatile("s_barrier" ::: "memory");
#pragma unroll
    for (int mm = 0; mm < 4; mm++) { a[mm][0] = rdA(1, 4 + mm, 0); a[mm][1] = rdA(1, 4 + mm, 1); }
    stageB(t1 + 2, 1, 0);
    asm volatile("s_barrier" ::: "memory");
    phase_mfma8<1, 1>(a, b, acc);
    asm volatile("s_barrier" ::: "memory");
    stageB(t1 + 2, 1, 1);
    asm volatile("s_barrier" ::: "memory");
    phase_mfma8<1, 0>(a, b, acc);
    asm volatile("s_waitcnt vmcnt(4)" ::: "memory");
    asm volatile("s_barrier" ::: "memory");
  }

  const bool side = (col0 >= 1024);
  const float* bias = side ? bias1 : bias0;
  unsigned short* C = side ? C1 : C0;
  const int cb = col0 - (side ? 1024 : 0);
#pragma unroll
  for (int n = 0; n < 4; n++) {
    int col = cb + wc * 64 + n * 16 + fm;
    float bv = bias[col];
#pragma unroll
    for (int m = 0; m < 8; m++) {
      int rbase = row0 + wr * 128 + m * 16 + quad * 4;
#pragma unroll
      for (int r = 0; r < 4; r++) {
        float val = acc[m][n][r] + bv;
        val = side ? tanhf(val) : fmaxf(val, 0.0f);
        C[(size_t)(rbase + r) * 1024 + col] = f2bf(val);
      }
    }
  }
}

// ---------------------------------------------------------------------------
// Stage: G7 128x128-tile 2-phase GEMM (r9-proven core) + fused DDPM update.
// LDS: As [2][4096] @lds, Bs [2][4096] @lds+8192 (32 KiB). 256 blocks.
// ---------------------------------------------------------------------------
__device__ __forceinline__ void stage_update(
    const unsigned short* A, const unsigned short* Bt, const float* bias,
    const unsigned short* d0, const unsigned short* d1,
    float* x, unsigned short* xbf,
    const float* a_amp, const float* b_amp, const float* phc,
    float coh, float c1, float sqa, float sigma, int add_noise,
    uint32_t k0, uint32_t k1, unsigned short* lds) {
  unsigned short* As = lds;          // [2][4096]
  unsigned short* Bs = lds + 8192;   // [2][4096]
  const int tid = threadIdx.x;
  const int wave = tid >> 6, lane = tid & 63;
  const int wr = wave >> 1, wc = wave & 1;   // 32-row band / 64-col band
  const int srow = tid >> 2;                 // 0..127
  const int sgr = (tid & 3) * 8;
  const int fm = lane & 15, quad = lane >> 4;
  const int id = blockIdx.x;
  const int nid = (id & 7) * 32 + (id >> 3);
  const int row0 = (nid & 63) << 7;
  const int col0 = (nid >> 6) << 7;

  auto issue = [&](int kt, int buf) {
    const int kk = kt * 32;
    gload16(A + (size_t)(row0 + srow) * 1024 + kk + sgr,
            As + buf * 4096 + srow * 32 + sgr);
    gload16(Bt + (size_t)(col0 + srow) * 1024 + kk + sgr,
            Bs + buf * 4096 + srow * 32 + sgr);
  };

  floatx4 acc[2][4];
#pragma unroll
  for (int tm = 0; tm < 2; tm++)
#pragma unroll
    for (int tn = 0; tn < 4; tn++) acc[tm][tn] = (floatx4){0.f, 0.f, 0.f, 0.f};

  const int nk = 32;  // K = 1024
  issue(0, 0);
#pragma unroll 1
  for (int k = 0; k < nk; k++) {
    const int cur = k & 1;
    if (k + 1 < nk) {
      issue(k + 1, cur ^ 1);
      asm volatile("s_waitcnt vmcnt(2)\ns_barrier" ::: "memory");
    } else {
      asm volatile("s_waitcnt vmcnt(0)\ns_barrier" ::: "memory");
    }
    bf16x8 a[2], b[4];
#pragma unroll
    for (int tm = 0; tm < 2; tm++)
      a[tm] = *(const bf16x8*)(&As[cur * 4096 + (wr * 32 + tm * 16 + fm) * 32 + quad * 8]);
#pragma unroll
    for (int tn = 0; tn < 4; tn++)
      b[tn] = *(const bf16x8*)(&Bs[cur * 4096 + (wc * 64 + tn * 16 + fm) * 32 + quad * 8]);
#pragma unroll
    for (int tm = 0; tm < 2; tm++)
#pragma unroll
      for (int tn = 0; tn < 4; tn++)
        acc[tm][tn] = __builtin_amdgcn_mfma_f32_16x16x32_bf16(a[tm], b[tn],
                                                              acc[tm][tn], 0, 0, 0);
    asm volatile("s_barrier" ::: "memory");
  }

  float aa = a_amp[0], bb = b_amp[0], pc = phc[0];
  float a2 = aa * aa, b2 = bb * bb, s = a2 + b2;
  float p0 = a2 / s, p1 = b2 / s;
  float sp0 = sqrtf(p0), sp1 = sqrtf(p1);
  float qi = 2.0f * sqrtf(p0 * p1) * pc * coh;
  float nscale = sigma + 0.1f * fabsf(qi);

#pragma unroll
  for (int tn = 0; tn < 4; tn++) {
    int col = col0 + wc * 64 + tn * 16 + fm;
    float bv = bias[col];
#pragma unroll
    for (int tm = 0; tm < 2; tm++) {
      int rbase = row0 + wr * 32 + tm * 16 + quad * 4;
#pragma unroll
      for (int r = 0; r < 4; r++) {
        int row = rbase + r;
        size_t i = (size_t)row * 512 + col;
        float itf = acc[tm][tn][r] + bv;
        float den = sp0 * bf2f(d0[i]) + sp1 * bf2f(d1[i]) + qi * itf;
        float xn = (x[i] - c1 * den) / sqa;
        if (add_noise) xn += nscale * tf_normal(k0, k1, (uint32_t)i);
        x[i] = xn;
        xbf[i] = f2bf(xn);
      }
    }
  }
}

// ---------------------------------------------------------------------------
// MEGA kernel: all 50 steps, 5 stages each, grid.sync between stages.
// Grid 256 x 512 threads, 128 KiB LDS, cooperative launch.
// ---------------------------------------------------------------------------
__global__ __launch_bounds__(512, 2)
void mega_kernel(unsigned short* xbf, float* x,
                 unsigned short* qf, unsigned short* h0, unsigned short* h1,
                 unsigned short* d0, unsigned short* d1,
                 const unsigned short* Wq_t, const unsigned short* WA_t,
                 const unsigned short* W02_t, const unsigned short* W12_t,
                 const unsigned short* Wi1_t, const unsigned short* Wi2_t,
                 const float* bq, const float* b01, const float* b11,
                 const float* b02, const float* b12, const float* bi1,
                 const float* bi2, const float* a_amp, const float* b_amp,
                 const float* phc) {
  __shared__ unsigned short LDS[65536];   // 128 KiB
  cg::grid_group grid = cg::this_grid();
  float coh = 1.0f;
  const float decay = 0.90483741803596f;  // expf(-0.1f)

#pragma unroll 1
  for (int j = 0; j < 50; j++) {
    const int t = 49 - j;
    // G1: qf = relu(xbf @ Wq + bq)
    stage_128x256<1, 0>(xbf, xbf, 512, 512, 512, 512, Wq_t, bq, qf, 1024,
                        nullptr, nullptr, nullptr, nullptr, LDS);
    __threadfence(); grid.sync();
    // G2: h0 = relu(qf@W01+b01), h1 = tanh(qf@W11+b11)
    stage_g2(qf, WA_t, b01, b11, h0, h1, LDS);
    __threadfence(); grid.sync();
    // G45: d0 = h0@W02+b02 ; d1 = h1@W12+b12
    stage_128x256<0, 1>(h0, h0, 1024, 1024, 1024, 1024, W02_t, b02, d0, 512,
                        h1, W12_t, b12, d1, LDS);
    __threadfence(); grid.sync();
    // G6: qf = gelu([d0|d1] @ Wi1 + bi1)
    stage_128x256<3, 0>(d0, d1, 512, 512, 512, 1024, Wi1_t, bi1, qf, 1024,
                        nullptr, nullptr, nullptr, nullptr, LDS);
    __threadfence(); grid.sync();
    // per-step scalars (bit-identical to the old host loop)
    float schedt = (float)(1e-4 + (0.02 - 1e-4) * (double)t / 99.0);
    float alphaf = fmaxf(1.0f - schedt, 1e-8f);
    float one_m_alpha = 1.0f - alphaf;
    float sqrt_1ma = sqrtf(fmaxf(one_m_alpha, 1e-8f));
    float c1v = one_m_alpha / sqrt_1ma;
    float sqa = sqrtf(alphaf);
    float sigma = 0.0f;
    if (t > 0) {
      float ap = 1.0f - (float)(1e-4 + (0.02 - 1e-4) * (double)(t - 1) / 99.0);
      sigma = sqrtf(fmaxf((1.0f - ap) / one_m_alpha * (1.0f - alphaf / ap), 0.0f));
    }
    uint32_t kt0, kt1; tf2x32(0u, 1u, 0u, (uint32_t)t, kt0, kt1);
    // G7: itf = qf @ Wi2 + bi2  +  DDPM update of x/xbf
    stage_update(qf, Wi2_t, bi2, d0, d1, x, xbf, a_amp, b_amp, phc,
                 coh, c1v, sqa, sigma, (t > 0) ? 1 : 0, kt0, kt1, LDS);
    coh *= decay;
    if (j != 49) { __threadfence(); grid.sync(); }
  }
}

__global__ void init_normal_kernel(float* __restrict__ x,
                                   unsigned short* __restrict__ xbf,
                                   uint32_t k0, uint32_t k1, int n) {
  int i = blockIdx.x * blockDim.x + threadIdx.x;
  if (i >= n) return;
  float v = tf_normal(k0, k1, (uint32_t)i);
  x[i] = v;
  xbf[i] = f2bf(v);
}

__global__ void final_kernel(const float* __restrict__ x,
                             const float* __restrict__ real,
                             float* __restrict__ out,
                             const float* __restrict__ a_amp,
                             const float* __restrict__ b_amp,
                             uint32_t k0, uint32_t k1, int n) {
  int i = blockIdx.x * blockDim.x + threadIdx.x;
  if (i >= n) return;
  float aa = a_amp[0], bb = b_amp[0];
  float a2 = aa * aa, b2 = bb * bb;
  float p0 = a2 / (a2 + b2);
  uint32_t o0, o1;
  tf2x32(k0, k1, 0u, 0u, o0, o1);
  uint32_t bits = o0 ^ o1;
  float u = __uint_as_float(0x3F800000u | (bits >> 9)) - 1.0f;
  float xv = x[i];
  out[i] = (u < p0) ? (0.7f * xv + 0.3f * real[i]) : xv;
}

extern "C" void kernel_launch(void* const* d_in, const int* in_sizes, int n_in,
                              void* d_out, int out_size, void* d_ws,
                              size_t ws_size, hipStream_t stream) {
  const float* real = (const float*)d_in[0];
  const float* Wq  = (const float*)d_in[2];
  const float* bq  = (const float*)d_in[3];
  const float* W01 = (const float*)d_in[4];
  const float* b01 = (const float*)d_in[5];
  const float* W02 = (const float*)d_in[6];
  const float* b02 = (const float*)d_in[7];
  const float* W11 = (const float*)d_in[8];
  const float* b11 = (const float*)d_in[9];
  const float* W12 = (const float*)d_in[10];
  const float* b12 = (const float*)d_in[11];
  const float* Wi1 = (const float*)d_in[12];
  const float* bi1 = (const float*)d_in[13];
  const float* Wi2 = (const float*)d_in[14];
  const float* bi2 = (const float*)d_in[15];
  const float* a_amp = (const float*)d_in[16];
  const float* b_amp = (const float*)d_in[17];
  const float* ph    = (const float*)d_in[18];

  const int Nn = 8192, F = 512, H = 1024;
  const int nElem = Nn * F;  // 4,194,304

  // workspace layout
  char* ws = (char*)d_ws;
  float* x = (float*)ws;                                   ws += (size_t)nElem * 4;
  unsigned short* xbf = (unsigned short*)ws;               ws += (size_t)nElem * 2;
  unsigned short* qf  = (unsigned short*)ws;               ws += (size_t)Nn * H * 2;
  unsigned short* h0  = (unsigned short*)ws;               ws += (size_t)Nn * H * 2;
  unsigned short* h1  = (unsigned short*)ws;               ws += (size_t)Nn * H * 2;
  unsigned short* d0  = (unsigned short*)ws;               ws += (size_t)nElem * 2;
  unsigned short* d1  = (unsigned short*)ws;               ws += (size_t)nElem * 2;
  unsigned short* Wq_t  = (unsigned short*)ws;             ws += (size_t)F * H * 2;
  unsigned short* WA_t  = (unsigned short*)ws;             ws += (size_t)(2 * H) * H * 2; // [W01_t ; W11_t]
  unsigned short* W02_t = (unsigned short*)ws;             ws += (size_t)H * F * 2;
  unsigned short* W12_t = (unsigned short*)ws;             ws += (size_t)H * F * 2;
  unsigned short* Wi1_t = (unsigned short*)ws;             ws += (size_t)(2 * F) * H * 2;
  unsigned short* Wi2_t = (unsigned short*)ws;             ws += (size_t)H * F * 2;

  dim3 tb(256);
  transpose_bf16_kernel<<<dim3(F / 32, H / 32), tb, 0, stream>>>(Wq, Wq_t, F, H);
  transpose_bf16_kernel<<<dim3(H / 32, H / 32), tb, 0, stream>>>(W01, WA_t, H, H);
  transpose_bf16_kernel<<<dim3(H / 32, H / 32), tb, 0, stream>>>(W11, WA_t + (size_t)H * H, H, H);
  transpose_bf16_kernel<<<dim3(H / 32, F / 32), tb, 0, stream>>>(W02, W02_t, H, F);
  transpose_bf16_kernel<<<dim3(H / 32, F / 32), tb, 0, stream>>>(W12, W12_t, H, F);
  transpose_bf16_kernel<<<dim3(2 * F / 32, H / 32), tb, 0, stream>>>(Wi1, Wi1_t, 2 * F, H);
  transpose_bf16_kernel<<<dim3(H / 32, F / 32), tb, 0, stream>>>(Wi2, Wi2_t, H, F);

  uint32_t kx0, kx1; tf2x32(0u, 1u, 0u, 10000u, kx0, kx1);
  init_normal_kernel<<<(nElem + 255) / 256, 256, 0, stream>>>(x, xbf, kx0, kx1, nElem);

  // --- mega cooperative launch: entire 50-step loop in one kernel ---
  void* kargs[] = {
    (void*)&xbf, (void*)&x, (void*)&qf, (void*)&h0, (void*)&h1,
    (void*)&d0, (void*)&d1,
    (void*)&Wq_t, (void*)&WA_t, (void*)&W02_t, (void*)&W12_t,
    (void*)&Wi1_t, (void*)&Wi2_t,
    (void*)&bq, (void*)&b01, (void*)&b11, (void*)&b02, (void*)&b12,
    (void*)&bi1, (void*)&bi2, (void*)&a_amp, (void*)&b_amp, (void*)&ph
  };
  hipLaunchCooperativeKernel((void*)mega_kernel, dim3(256), dim3(512),
                             kargs, 0, stream);

  uint32_t ku0, ku1; tf2x32(0u, 1u, 0u, 99999u, ku0, ku1);
  final_kernel<<<(nElem + 255) / 256, 256, 0, stream>>>(
      x, real, (float*)d_out, a_amp, b_amp, ku0, ku1, nElem);
}

// Round 6
// 8049.162 us; speedup vs baseline: 5.1462x; 5.1462x over previous
//
#include <hip/hip_runtime.h>
#include <stdint.h>
#include <math.h>

// ---------------------------------------------------------------------------
// QuantumDiffusionDreamer — round 16: REVERT to r13 (measured 8060 µs, best).
// r15 mega-fusion (one cooperative kernel, 250 grid.sync) regressed 5.1x:
// counters showed MfmaUtil 4%, 636 MB/step HBM (3x ideal), ~145 µs/sync —
// grid.sync on 8-XCD MI355X flushes L2 (non-coherent XCDs) and quiesces the
// machine. LESSON: never grid.sync at sub-ms stage granularity on this chip.
// Structure here = r13: per-step dispatches
//   G1 (128x256 8ph) -> G2 (256^2 8ph) -> G45 (128x256 8ph z-pair)
//   -> G6 (128x256 8ph A-split) -> G7 (64x128 2ph + fused DDPM epilogue)
// all hardware-verified (r12: 8124, r13: 8060, both passed, absmax 0.015625).
// ---------------------------------------------------------------------------

typedef __bf16 bf16x8 __attribute__((ext_vector_type(8)));
typedef float floatx4 __attribute__((ext_vector_type(4)));

__host__ __device__ inline void tf2x32(uint32_t k0, uint32_t k1,
                                       uint32_t x0, uint32_t x1,
                                       uint32_t& o0, uint32_t& o1) {
  uint32_t ks2 = k0 ^ k1 ^ 0x1BD11BDAu;
#define TF_R(r) { x0 += x1; x1 = (x1 << (r)) | (x1 >> (32 - (r))); x1 ^= x0; }
  x0 += k0; x1 += k1;
  TF_R(13) TF_R(15) TF_R(26) TF_R(6)
  x0 += k1;  x1 += ks2 + 1u;
  TF_R(17) TF_R(29) TF_R(16) TF_R(24)
  x0 += ks2; x1 += k0 + 2u;
  TF_R(13) TF_R(15) TF_R(26) TF_R(6)
  x0 += k0;  x1 += k1 + 3u;
  TF_R(17) TF_R(29) TF_R(16) TF_R(24)
  x0 += k1;  x1 += ks2 + 4u;
  TF_R(13) TF_R(15) TF_R(26) TF_R(6)
  x0 += ks2; x1 += k0 + 5u;
#undef TF_R
  o0 = x0; o1 = x1;
}

__device__ inline float erfinv_f32(float x) {
  float w = -log1pf(-x * x);
  float p;
  if (w < 5.0f) {
    w = w - 2.5f;
    p = 2.81022636e-08f;
    p = fmaf(p, w, 3.43273939e-07f);
    p = fmaf(p, w, -3.5233877e-06f);
    p = fmaf(p, w, -4.39150654e-06f);
    p = fmaf(p, w, 0.00021858087f);
    p = fmaf(p, w, -0.00125372503f);
    p = fmaf(p, w, -0.00417768164f);
    p = fmaf(p, w, 0.246640727f);
    p = fmaf(p, w, 1.50140941f);
  } else {
    w = sqrtf(w) - 3.0f;
    p = -0.000200214257f;
    p = fmaf(p, w, 0.000100950558f);
    p = fmaf(p, w, 0.00134934322f);
    p = fmaf(p, w, -0.00367342844f);
    p = fmaf(p, w, 0.00573950773f);
    p = fmaf(p, w, -0.0076224613f);
    p = fmaf(p, w, 0.00943887047f);
    p = fmaf(p, w, 1.00167406f);
    p = fmaf(p, w, 2.83297682f);
  }
  return p * x;
}

__device__ inline float tf_normal(uint32_t k0, uint32_t k1, uint32_t i) {
  uint32_t o0, o1;
  tf2x32(k0, k1, 0u, i, o0, o1);
  uint32_t bits = o0 ^ o1;  // partitionable random_bits path
  float f = __uint_as_float(0x3F800000u | (bits >> 9)) - 1.0f;  // [0,1)
  float u = f * 2.0f + (-0.99999994f);
  u = fmaxf(-0.99999994f, u);
  return 1.41421356f * erfinv_f32(u);
}

__device__ inline unsigned short f2bf(float f) {
  uint32_t u = __float_as_uint(f);
  u += 0x7FFFu + ((u >> 16) & 1u);   // round-to-nearest-even
  return (unsigned short)(u >> 16);
}
__device__ inline float bf2f(unsigned short h) {
  return __uint_as_float(((uint32_t)h) << 16);
}

// ---------------------------------------------------------------------------
// Weight transpose + bf16 convert: Wt[n][k] = bf16(W[k][n]);  W is [K,N] fp32.
// ---------------------------------------------------------------------------
__global__ __launch_bounds__(256)
void transpose_bf16_kernel(const float* __restrict__ W,
                           unsigned short* __restrict__ Wt, int K, int N) {
  __shared__ float tile[32][33];
  int kb = blockIdx.x * 32, nb = blockIdx.y * 32;
  int tx = threadIdx.x & 31, ty = threadIdx.x >> 5;
#pragma unroll
  for (int i = 0; i < 32; i += 8)
    tile[ty + i][tx] = W[(size_t)(kb + ty + i) * N + nb + tx];
  __syncthreads();
#pragma unroll
  for (int i = 0; i < 32; i += 8)
    Wt[(size_t)(nb + ty + i) * K + kb + tx] = f2bf(tile[tx][ty + i]);
}

// ---------------------------------------------------------------------------
// Shared 8-phase MFMA phase helpers (T5 setprio; rule-18 sched_barrier).
// ---------------------------------------------------------------------------
template<int MH, int NH>
__device__ __forceinline__ void phase_mfma8(bf16x8 (&a)[4][2], bf16x8 (&b)[4][2],
                                            floatx4 (&acc)[8][4]) {
  asm volatile("s_waitcnt lgkmcnt(0)" ::: "memory");
  __builtin_amdgcn_sched_barrier(0);
  __builtin_amdgcn_s_setprio(1);
#pragma unroll
  for (int s = 0; s < 2; s++)
#pragma unroll
    for (int mm = 0; mm < 4; mm++)
#pragma unroll
      for (int nn = 0; nn < 2; nn++)
        acc[MH * 4 + mm][NH * 2 + nn] = __builtin_amdgcn_mfma_f32_16x16x32_bf16(
            a[mm][s], b[NH * 2 + nn][s], acc[MH * 4 + mm][NH * 2 + nn], 0, 0, 0);
  __builtin_amdgcn_s_setprio(0);
}

template<int MH, int NH>
__device__ __forceinline__ void phase_mfma4(bf16x8 (&a)[4][2], bf16x8 (&b)[4][2],
                                            floatx4 (&acc)[4][4]) {
  asm volatile("s_waitcnt lgkmcnt(0)" ::: "memory");
  __builtin_amdgcn_sched_barrier(0);
  __builtin_amdgcn_s_setprio(1);
#pragma unroll
  for (int s = 0; s < 2; s++)
#pragma unroll
    for (int mm = 0; mm < 2; mm++)
#pragma unroll
      for (int nn = 0; nn < 2; nn++)
        acc[MH * 2 + mm][NH * 2 + nn] = __builtin_amdgcn_mfma_f32_16x16x32_bf16(
            a[MH * 2 + mm][s], b[NH * 2 + nn][s], acc[MH * 2 + mm][NH * 2 + nn],
            0, 0, 0);
  __builtin_amdgcn_s_setprio(0);
}

// ---------------------------------------------------------------------------
// 128x256-tile 8-phase GEMM (G1 / G45 / G6). 512 threads = 8 waves (2Mx4N),
// per-wave 64x64 output, acc[4][4]. BK=64, LDS = 2x(128x64 + 256x64) bf16 =
// 96 KiB -> 1 block/CU. Grid 256 blocks, XCD-chunked. K runtime (mult of 128).
// A-split over K at K0 (for G6's [d0|d1] concat); PAIR selects the z-GEMM.
// ACT: 0 none, 1 relu, 3 gelu(exact).
// ---------------------------------------------------------------------------
template<int ACT, int PAIR>
__global__ __launch_bounds__(512, 2)
void mfma_gemm_8ph_128x256(const unsigned short* __restrict__ A0,
                           const unsigned short* __restrict__ A1,
                           int lda0, int lda1, int K0, int Ktot,
                           const unsigned short* __restrict__ Bt,
                           const float* __restrict__ bias,
                           unsigned short* __restrict__ C, int ldc,
                           const unsigned short* __restrict__ Ab,
                           const unsigned short* __restrict__ Btb,
                           const float* __restrict__ biasb,
                           unsigned short* __restrict__ Cb) {
  __shared__ unsigned short As[2][128 * 64];   // 32 KiB
  __shared__ unsigned short Bs[2][256 * 64];   // 64 KiB
  const int tid = threadIdx.x;
  const int wave = tid >> 6, lane = tid & 63;
  const int wr = wave >> 2, wc = wave & 3;     // 64-row band / 64-col band
  const int fm = lane & 15, quad = lane >> 4;
  const int id = blockIdx.x;
  const int nid = (id & 7) * 32 + (id >> 3);   // XCD-chunked (256 blocks)
  int row0, col0;
  if (PAIR) {
    const int rem = nid & 127;
    row0 = (rem & 63) << 7;
    col0 = (rem >> 6) << 8;
    if (nid >> 7) { A0 = Ab; A1 = Ab; Bt = Btb; bias = biasb; C = Cb; }
  } else {
    row0 = (nid & 63) << 7;
    col0 = (nid >> 6) << 8;
  }
  const int NKT = Ktot >> 6;

  // A half-tile = 64 rows x 64 cols = 512 granules -> 1 load/thread.
  auto stageA = [&](int tile, int buf, int h) {
    if (tile >= NKT) return;
    const int kk = tile << 6;
    const unsigned short* Ap; int kOff, lda;
    if (kk < K0) { Ap = A0; kOff = kk; lda = lda0; }
    else         { Ap = A1; kOff = kk - K0; lda = lda1; }
    const int sr = tid >> 3, gc = tid & 7;
    __builtin_amdgcn_global_load_lds(
        (const __attribute__((address_space(1))) uint32_t*)
            (Ap + (size_t)(row0 + h * 64 + sr) * lda + kOff + ((gc ^ (sr & 7)) << 3)),
        (__attribute__((address_space(3))) uint32_t*)(&As[buf][h * 4096 + tid * 8]),
        16, 0, 0);
  };
  // B half-tile = 128 rows x 64 cols = 1024 granules -> 2 loads/thread.
  auto stageB = [&](int tile, int buf, int h) {
    if (tile >= NKT) return;
    const int kk = tile << 6;
#pragma unroll
    for (int c = 0; c < 2; c++) {
      int g2 = c * 512 + tid;
      int sr = g2 >> 3, gc = g2 & 7;
      __builtin_amdgcn_global_load_lds(
          (const __attribute__((address_space(1))) uint32_t*)
              (Bt + (size_t)(col0 + h * 128 + sr) * Ktot + kk + ((gc ^ (sr & 7)) << 3)),
          (__attribute__((address_space(3))) uint32_t*)(&Bs[buf][h * 8192 + g2 * 8]),
          16, 0, 0);
    }
  };

  const int aswz = (fm & 7) << 3;   // row&7 == fm&7 (64-row bands, 16-row frags)
  auto rdA = [&](int buf, int m, int s) {
    return *(const bf16x8*)(&As[buf][(wr * 64 + m * 16 + fm) * 64 +
                                     ((s * 32 + quad * 8) ^ aswz)]);
  };
  auto rdB = [&](int buf, int n, int s) {
    return *(const bf16x8*)(&Bs[buf][(wc * 64 + n * 16 + fm) * 64 +
                                     ((s * 32 + quad * 8) ^ aswz)]);
  };

  floatx4 acc[4][4];
#pragma unroll
  for (int m = 0; m < 4; m++)
#pragma unroll
    for (int n = 0; n < 4; n++) acc[m][n] = (floatx4){0.f, 0.f, 0.f, 0.f};

  // prologue: tile0 full (6 loads/thr) + tile1 B (4 loads/thr)
  stageA(0, 0, 0); stageA(0, 0, 1);
  stageB(0, 0, 0); stageB(0, 0, 1);
  stageB(1, 1, 0); stageB(1, 1, 1);
  asm volatile("s_waitcnt vmcnt(4)" ::: "memory");
  asm volatile("s_barrier" ::: "memory");

  const int NJ = NKT >> 1;
#pragma unroll 1
  for (int j = 0; j < NJ; j++) {
    const int t1 = 2 * j + 1;
    bf16x8 a[4][2], b[4][2];
    // ================= K-tile 2j (buf 0) =================
    // ph1 (MH0,NH0): a0,a1 + b0,b1 (8 reads); stage A(t1)h0
#pragma unroll
    for (int mm = 0; mm < 2; mm++) { a[mm][0] = rdA(0, mm, 0); a[mm][1] = rdA(0, mm, 1); }
#pragma unroll
    for (int nn = 0; nn < 2; nn++) { b[nn][0] = rdB(0, nn, 0); b[nn][1] = rdB(0, nn, 1); }
    stageA(t1, 1, 0);
    asm volatile("s_barrier" ::: "memory");
    phase_mfma4<0, 0>(a, b, acc);
    asm volatile("s_barrier" ::: "memory");
    // ph2 (MH0,NH1): b2,b3; stage A(t1)h1
#pragma unroll
    for (int nn = 2; nn < 4; nn++) { b[nn][0] = rdB(0, nn, 0); b[nn][1] = rdB(0, nn, 1); }
    stageA(t1, 1, 1);
    asm volatile("s_barrier" ::: "memory");
    phase_mfma4<0, 1>(a, b, acc);
    asm volatile("s_barrier" ::: "memory");
    // ph3 (MH1,NH1): a2,a3 (B of buf0 free after ph2 -> stage B next2)
#pragma unroll
    for (int mm = 2; mm < 4; mm++) { a[mm][0] = rdA(0, mm, 0); a[mm][1] = rdA(0, mm, 1); }
    stageB(t1 + 1, 0, 0);
    asm volatile("s_barrier" ::: "memory");
    phase_mfma4<1, 1>(a, b, acc);
    asm volatile("s_barrier" ::: "memory");
    // ph4 (MH1,NH0): 0 reads; K-tile boundary vmcnt
    stageB(t1 + 1, 0, 1);
    asm volatile("s_barrier" ::: "memory");
    phase_mfma4<1, 0>(a, b, acc);
    if (j == NJ - 1) asm volatile("s_waitcnt vmcnt(0)" ::: "memory");
    else             asm volatile("s_waitcnt vmcnt(4)" ::: "memory");
    asm volatile("s_barrier" ::: "memory");
    // ================= K-tile 2j+1 (buf 1) =================
    // ph5 (A of buf0 free after ph3 -> stage A next2 into buf0)
#pragma unroll
    for (int mm = 0; mm < 2; mm++) { a[mm][0] = rdA(1, mm, 0); a[mm][1] = rdA(1, mm, 1); }
#pragma unroll
    for (int nn = 0; nn < 2; nn++) { b[nn][0] = rdB(1, nn, 0); b[nn][1] = rdB(1, nn, 1); }
    stageA(t1 + 1, 0, 0);
    asm volatile("s_barrier" ::: "memory");
    phase_mfma4<0, 0>(a, b, acc);
    asm volatile("s_barrier" ::: "memory");
    // ph6
#pragma unroll
    for (int nn = 2; nn < 4; nn++) { b[nn][0] = rdB(1, nn, 0); b[nn][1] = rdB(1, nn, 1); }
    stageA(t1 + 1, 0, 1);
    asm volatile("s_barrier" ::: "memory");
    phase_mfma4<0, 1>(a, b, acc);
    asm volatile("s_barrier" ::: "memory");
    // ph7
#pragma unroll
    for (int mm = 2; mm < 4; mm++) { a[mm][0] = rdA(1, mm, 0); a[mm][1] = rdA(1, mm, 1); }
    stageB(t1 + 2, 1, 0);
    asm volatile("s_barrier" ::: "memory");
    phase_mfma4<1, 1>(a, b, acc);
    asm volatile("s_barrier" ::: "memory");
    // ph8
    stageB(t1 + 2, 1, 1);
    asm volatile("s_barrier" ::: "memory");
    phase_mfma4<1, 0>(a, b, acc);
    asm volatile("s_waitcnt vmcnt(4)" ::: "memory");
    asm volatile("s_barrier" ::: "memory");
  }

  // epilogue
#pragma unroll
  for (int n = 0; n < 4; n++) {
    int col = col0 + wc * 64 + n * 16 + fm;
    float bv = bias[col];
#pragma unroll
    for (int m = 0; m < 4; m++) {
      int rbase = row0 + wr * 64 + m * 16 + quad * 4;
#pragma unroll
      for (int r = 0; r < 4; r++) {
        float val = acc[m][n][r] + bv;
        if (ACT == 1) val = fmaxf(val, 0.0f);
        if (ACT == 3) val = 0.5f * val * (1.0f + erff(val * 0.70710678118654752f));
        C[(size_t)(rbase + r) * ldc + col] = f2bf(val);
      }
    }
  }
}

// ---------------------------------------------------------------------------
// G2 dedicated: 256x256-tile 8-phase schedule (r12, hardware-verified).
// C = act(qf[8192,1024] @ WA[1024,2048] + bias), split relu->h0 / tanh->h1.
// ---------------------------------------------------------------------------
__global__ __launch_bounds__(512, 2)
void mfma_gemm2_8ph(const unsigned short* __restrict__ A,   // qf [8192,1024]
                    const unsigned short* __restrict__ Bt,  // WA_t [2048,1024]
                    const float* __restrict__ bias0,        // b01
                    const float* __restrict__ bias1,        // b11
                    unsigned short* __restrict__ C0,        // h0 [8192,1024]
                    unsigned short* __restrict__ C1) {      // h1 [8192,1024]
  constexpr int NKT = 16;   // K=1024 / BK=64
  __shared__ unsigned short As[2][256 * 64];   // [buf][row*64 + swz-col]
  __shared__ unsigned short Bs[2][256 * 64];
  const int tid = threadIdx.x;
  const int wave = tid >> 6, lane = tid & 63;
  const int wr = wave >> 2, wc = wave & 3;       // 128-row band / 64-col band
  const int fm = lane & 15, quad = lane >> 4;
  const int id = blockIdx.x;
  const int nid = (id & 7) * 32 + (id >> 3);
  const int row0 = (nid & 31) << 8;
  const int col0 = (nid >> 5) << 8;

  auto stageA = [&](int tile, int buf, int h) {
    if (tile >= NKT) return;
    const int kk = tile << 6;
#pragma unroll
    for (int c = 0; c < 2; c++) {
      int g2 = c * 512 + tid;
      int sr = g2 >> 3, gc = g2 & 7;
      __builtin_amdgcn_global_load_lds(
          (const __attribute__((address_space(1))) uint32_t*)
              (A + (size_t)(row0 + h * 128 + sr) * 1024 + kk + ((gc ^ (sr & 7)) << 3)),
          (__attribute__((address_space(3))) uint32_t*)(&As[buf][h * 8192 + g2 * 8]),
          16, 0, 0);
    }
  };
  auto stageB = [&](int tile, int buf, int h) {
    if (tile >= NKT) return;
    const int kk = tile << 6;
#pragma unroll
    for (int c = 0; c < 2; c++) {
      int g2 = c * 512 + tid;
      int sr = g2 >> 3, gc = g2 & 7;
      __builtin_amdgcn_global_load_lds(
          (const __attribute__((address_space(1))) uint32_t*)
              (Bt + (size_t)(col0 + h * 128 + sr) * 1024 + kk + ((gc ^ (sr & 7)) << 3)),
          (__attribute__((address_space(3))) uint32_t*)(&Bs[buf][h * 8192 + g2 * 8]),
          16, 0, 0);
    }
  };

  const int aswz = (fm & 7) << 3;
  auto rdA = [&](int buf, int m, int s) {
    return *(const bf16x8*)(&As[buf][(wr * 128 + m * 16 + fm) * 64 +
                                     ((s * 32 + quad * 8) ^ aswz)]);
  };
  auto rdB = [&](int buf, int n, int s) {
    return *(const bf16x8*)(&Bs[buf][(wc * 64 + n * 16 + fm) * 64 +
                                     ((s * 32 + quad * 8) ^ aswz)]);
  };

  floatx4 acc[8][4];
#pragma unroll
  for (int m = 0; m < 8; m++)
#pragma unroll
    for (int n = 0; n < 4; n++) acc[m][n] = (floatx4){0.f, 0.f, 0.f, 0.f};

  stageA(0, 0, 0); stageA(0, 0, 1);
  stageB(0, 0, 0); stageB(0, 0, 1);
  stageB(1, 1, 0); stageB(1, 1, 1);
  asm volatile("s_waitcnt vmcnt(4)" ::: "memory");
  asm volatile("s_barrier" ::: "memory");

#pragma unroll 1
  for (int j = 0; j < 8; j++) {
    const int t1 = 2 * j + 1;
    bf16x8 a[4][2], b[4][2];
    // ================= K-tile 2j (buf 0) =================
#pragma unroll
    for (int mm = 0; mm < 4; mm++) { a[mm][0] = rdA(0, mm, 0); a[mm][1] = rdA(0, mm, 1); }
#pragma unroll
    for (int nn = 0; nn < 2; nn++) { b[nn][0] = rdB(0, nn, 0); b[nn][1] = rdB(0, nn, 1); }
    stageA(t1, 1, 0);
    asm volatile("s_barrier" ::: "memory");
    phase_mfma8<0, 0>(a, b, acc);
    asm volatile("s_barrier" ::: "memory");
#pragma unroll
    for (int nn = 2; nn < 4; nn++) { b[nn][0] = rdB(0, nn, 0); b[nn][1] = rdB(0, nn, 1); }
    stageA(t1, 1, 1);
    asm volatile("s_barrier" ::: "memory");
    phase_mfma8<0, 1>(a, b, acc);
    asm volatile("s_barrier" ::: "memory");
#pragma unroll
    for (int mm = 0; mm < 4; mm++) { a[mm][0] = rdA(0, 4 + mm, 0); a[mm][1] = rdA(0, 4 + mm, 1); }
    stageB(t1 + 1, 0, 0);
    asm volatile("s_barrier" ::: "memory");
    phase_mfma8<1, 1>(a, b, acc);
    asm volatile("s_barrier" ::: "memory");
    stageB(t1 + 1, 0, 1);
    asm volatile("s_barrier" ::: "memory");
    phase_mfma8<1, 0>(a, b, acc);
    if (j == 7) asm volatile("s_waitcnt vmcnt(0)" ::: "memory");
    else        asm volatile("s_waitcnt vmcnt(4)" ::: "memory");
    asm volatile("s_barrier" ::: "memory");
    // ================= K-tile 2j+1 (buf 1) =================
#pragma unroll
    for (int mm = 0; mm < 4; mm++) { a[mm][0] = rdA(1, mm, 0); a[mm][1] = rdA(1, mm, 1); }
#pragma unroll
    for (int nn = 0; nn < 2; nn++) { b[nn][0] = rdB(1, nn, 0); b[nn][1] = rdB(1, nn, 1); }
    stageA(t1 + 1, 0, 0);
    asm volatile("s_barrier" ::: "memory");
    phase_mfma8<0, 0>(a, b, acc);
    asm volatile("s_barrier" ::: "memory");
#pragma unroll
    for (int nn = 2; nn < 4; nn++) { b[nn][0] = rdB(1, nn, 0); b[nn][1] = rdB(1, nn, 1); }
    stageA(t1 + 1, 0, 1);
    asm volatile("s_barrier" ::: "memory");
    phase_mfma8<0, 1>(a, b, acc);
    asm volatile("s_barrier" ::: "memory");
#pragma unroll
    for (int mm = 0; mm < 4; mm++) { a[mm][0] = rdA(1, 4 + mm, 0); a[mm][1] = rdA(1, 4 + mm, 1); }
    stageB(t1 + 2, 1, 0);
    asm volatile("s_barrier" ::: "memory");
    phase_mfma8<1, 1>(a, b, acc);
    asm volatile("s_barrier" ::: "memory");
    stageB(t1 + 2, 1, 1);
    asm volatile("s_barrier" ::: "memory");
    phase_mfma8<1, 0>(a, b, acc);
    asm volatile("s_waitcnt vmcnt(4)" ::: "memory");
    asm volatile("s_barrier" ::: "memory");
  }

  const bool side = (col0 >= 1024);
  const float* bias = side ? bias1 : bias0;
  unsigned short* C = side ? C1 : C0;
  const int cb = col0 - (side ? 1024 : 0);
#pragma unroll
  for (int n = 0; n < 4; n++) {
    int col = cb + wc * 64 + n * 16 + fm;
    float bv = bias[col];
#pragma unroll
    for (int m = 0; m < 8; m++) {
      int rbase = row0 + wr * 128 + m * 16 + quad * 4;
#pragma unroll
      for (int r = 0; r < 4; r++) {
        float val = acc[m][n][r] + bv;
        val = side ? tanhf(val) : fmaxf(val, 0.0f);
        C[(size_t)(rbase + r) * 1024 + col] = f2bf(val);
      }
    }
  }
}

// ---------------------------------------------------------------------------
// G7 fused: itf = hi @ Wi2 + bi2, then the full DDPM x-update in the
// epilogue. 64x128 tile, grid (4,128) = 512 blocks, 512 threads (8 waves of
// 32x32). 16 normals per thread at 16 waves/CU (r7 lesson respected).
// ---------------------------------------------------------------------------
__global__ __launch_bounds__(512, 4)
void mfma_gemm_update(const unsigned short* __restrict__ A,   // hi [8192,1024]
                      const unsigned short* __restrict__ Bt,  // Wi2_t [512][1024]
                      const float* __restrict__ bias,         // bi2
                      const unsigned short* __restrict__ d0,
                      const unsigned short* __restrict__ d1,
                      float* __restrict__ x,
                      unsigned short* __restrict__ xbf,
                      const float* __restrict__ a_amp,
                      const float* __restrict__ b_amp,
                      const float* __restrict__ ph,
                      float coh, float c1, float sqa, float sigma,
                      int add_noise, uint32_t k0, uint32_t k1) {
  __shared__ unsigned short As[2][64 * 32];
  __shared__ unsigned short Bs[2][128 * 32];
  const int tid = threadIdx.x;
  const int wave = tid >> 6, lane = tid & 63;
  const int wr = wave >> 2, wc = wave & 3;       // 32-row band / 32-col band
  const int fm = lane & 15, quad = lane >> 4;
  const int id = blockIdx.x + gridDim.x * blockIdx.y;
  const int row0 = (id & 127) << 6;
  const int col0 = (id >> 7) << 7;
  const int sArow = (tid & 255) >> 2;            // 0..63 (duplicated halves)
  const int sBrow = tid >> 2;                    // 0..127
  const int sgr = (tid & 3) * 8;

  auto issue = [&](int kt, int buf) {
    const int kk = kt * 32;
    __builtin_amdgcn_global_load_lds(
        (const __attribute__((address_space(1))) uint32_t*)
            (A + (size_t)(row0 + sArow) * 1024 + kk + sgr),
        (__attribute__((address_space(3))) uint32_t*)(&As[buf][sArow * 32 + sgr]),
        16, 0, 0);
    __builtin_amdgcn_global_load_lds(
        (const __attribute__((address_space(1))) uint32_t*)
            (Bt + (size_t)(col0 + sBrow) * 1024 + kk + sgr),
        (__attribute__((address_space(3))) uint32_t*)(&Bs[buf][sBrow * 32 + sgr]),
        16, 0, 0);
  };

  floatx4 acc[2][2];
#pragma unroll
  for (int tm = 0; tm < 2; tm++)
#pragma unroll
    for (int tn = 0; tn < 2; tn++) acc[tm][tn] = (floatx4){0.f, 0.f, 0.f, 0.f};

  const int nk = 32;  // K = 1024
  issue(0, 0);
  for (int k = 0; k < nk; k++) {
    const int cur = k & 1;
    if (k + 1 < nk) {
      issue(k + 1, cur ^ 1);
      asm volatile("s_waitcnt vmcnt(2)\ns_barrier" ::: "memory");
    } else {
      asm volatile("s_waitcnt vmcnt(0)\ns_barrier" ::: "memory");
    }
    bf16x8 a[2], b[2];
#pragma unroll
    for (int tm = 0; tm < 2; tm++)
      a[tm] = *(const bf16x8*)(&As[cur][(wr * 32 + tm * 16 + fm) * 32 + quad * 8]);
#pragma unroll
    for (int tn = 0; tn < 2; tn++)
      b[tn] = *(const bf16x8*)(&Bs[cur][(wc * 32 + tn * 16 + fm) * 32 + quad * 8]);
#pragma unroll
    for (int tm = 0; tm < 2; tm++)
#pragma unroll
      for (int tn = 0; tn < 2; tn++)
        acc[tm][tn] = __builtin_amdgcn_mfma_f32_16x16x32_bf16(a[tm], b[tn],
                                                              acc[tm][tn], 0, 0, 0);
    asm volatile("s_barrier" ::: "memory");
  }

  float aa = a_amp[0], bb = b_amp[0], pc = ph[0];
  float a2 = aa * aa, b2 = bb * bb, s = a2 + b2;
  float p0 = a2 / s, p1 = b2 / s;
  float sp0 = sqrtf(p0), sp1 = sqrtf(p1);
  float qi = 2.0f * sqrtf(p0 * p1) * pc * coh;
  float nscale = sigma + 0.1f * fabsf(qi);

#pragma unroll
  for (int tn = 0; tn < 2; tn++) {
    int col = col0 + wc * 32 + tn * 16 + fm;
    float bv = bias[col];
#pragma unroll
    for (int tm = 0; tm < 2; tm++) {
      int rbase = row0 + wr * 32 + tm * 16 + quad * 4;
#pragma unroll
      for (int r = 0; r < 4; r++) {
        int row = rbase + r;
        size_t i = (size_t)row * 512 + col;
        float itf = acc[tm][tn][r] + bv;
        float den = sp0 * bf2f(d0[i]) + sp1 * bf2f(d1[i]) + qi * itf;
        float xn = (x[i] - c1 * den) / sqa;
        if (add_noise) xn += nscale * tf_normal(k0, k1, (uint32_t)i);
        x[i] = xn;
        xbf[i] = f2bf(xn);
      }
    }
  }
}

__global__ void init_normal_kernel(float* __restrict__ x,
                                   unsigned short* __restrict__ xbf,
                                   uint32_t k0, uint32_t k1, int n) {
  int i = blockIdx.x * blockDim.x + threadIdx.x;
  if (i >= n) return;
  float v = tf_normal(k0, k1, (uint32_t)i);
  x[i] = v;
  xbf[i] = f2bf(v);
}

__global__ void final_kernel(const float* __restrict__ x,
                             const float* __restrict__ real,
                             float* __restrict__ out,
                             const float* __restrict__ a_amp,
                             const float* __restrict__ b_amp,
                             uint32_t k0, uint32_t k1, int n) {
  int i = blockIdx.x * blockDim.x + threadIdx.x;
  if (i >= n) return;
  float aa = a_amp[0], bb = b_amp[0];
  float a2 = aa * aa, b2 = bb * bb;
  float p0 = a2 / (a2 + b2);
  uint32_t o0, o1;
  tf2x32(k0, k1, 0u, 0u, o0, o1);
  uint32_t bits = o0 ^ o1;
  float u = __uint_as_float(0x3F800000u | (bits >> 9)) - 1.0f;
  float xv = x[i];
  out[i] = (u < p0) ? (0.7f * xv + 0.3f * real[i]) : xv;
}

extern "C" void kernel_launch(void* const* d_in, const int* in_sizes, int n_in,
                              void* d_out, int out_size, void* d_ws,
                              size_t ws_size, hipStream_t stream) {
  const float* real = (const float*)d_in[0];
  const float* Wq  = (const float*)d_in[2];
  const float* bq  = (const float*)d_in[3];
  const float* W01 = (const float*)d_in[4];
  const float* b01 = (const float*)d_in[5];
  const float* W02 = (const float*)d_in[6];
  const float* b02 = (const float*)d_in[7];
  const float* W11 = (const float*)d_in[8];
  const float* b11 = (const float*)d_in[9];
  const float* W12 = (const float*)d_in[10];
  const float* b12 = (const float*)d_in[11];
  const float* Wi1 = (const float*)d_in[12];
  const float* bi1 = (const float*)d_in[13];
  const float* Wi2 = (const float*)d_in[14];
  const float* bi2 = (const float*)d_in[15];
  const float* a_amp = (const float*)d_in[16];
  const float* b_amp = (const float*)d_in[17];
  const float* ph    = (const float*)d_in[18];

  const int Nn = 8192, F = 512, H = 1024;
  const int nElem = Nn * F;  // 4,194,304

  // workspace layout
  char* ws = (char*)d_ws;
  float* x = (float*)ws;                                   ws += (size_t)nElem * 4;
  unsigned short* xbf = (unsigned short*)ws;               ws += (size_t)nElem * 2;
  unsigned short* qf  = (unsigned short*)ws;               ws += (size_t)Nn * H * 2;
  unsigned short* h0  = (unsigned short*)ws;               ws += (size_t)Nn * H * 2;
  unsigned short* h1  = (unsigned short*)ws;               ws += (size_t)Nn * H * 2;
  unsigned short* d0  = (unsigned short*)ws;               ws += (size_t)nElem * 2;
  unsigned short* d1  = (unsigned short*)ws;               ws += (size_t)nElem * 2;
  unsigned short* Wq_t  = (unsigned short*)ws;             ws += (size_t)F * H * 2;
  unsigned short* WA_t  = (unsigned short*)ws;             ws += (size_t)(2 * H) * H * 2; // [W01_t ; W11_t]
  unsigned short* W02_t = (unsigned short*)ws;             ws += (size_t)H * F * 2;
  unsigned short* W12_t = (unsigned short*)ws;             ws += (size_t)H * F * 2;
  unsigned short* Wi1_t = (unsigned short*)ws;             ws += (size_t)(2 * F) * H * 2;
  unsigned short* Wi2_t = (unsigned short*)ws;             ws += (size_t)H * F * 2;

  dim3 tb(256);
  transpose_bf16_kernel<<<dim3(F / 32, H / 32), tb, 0, stream>>>(Wq, Wq_t, F, H);
  transpose_bf16_kernel<<<dim3(H / 32, H / 32), tb, 0, stream>>>(W01, WA_t, H, H);
  transpose_bf16_kernel<<<dim3(H / 32, H / 32), tb, 0, stream>>>(W11, WA_t + (size_t)H * H, H, H);
  transpose_bf16_kernel<<<dim3(H / 32, F / 32), tb, 0, stream>>>(W02, W02_t, H, F);
  transpose_bf16_kernel<<<dim3(H / 32, F / 32), tb, 0, stream>>>(W12, W12_t, H, F);
  transpose_bf16_kernel<<<dim3(2 * F / 32, H / 32), tb, 0, stream>>>(Wi1, Wi1_t, 2 * F, H);
  transpose_bf16_kernel<<<dim3(H / 32, F / 32), tb, 0, stream>>>(Wi2, Wi2_t, H, F);

  uint32_t kx0, kx1; tf2x32(0u, 1u, 0u, 10000u, kx0, kx1);
  init_normal_kernel<<<(nElem + 255) / 256, 256, 0, stream>>>(x, xbf, kx0, kx1, nElem);

  float sched[100];
  for (int i = 0; i < 100; i++)
    sched[i] = (float)(1e-4 + (0.02 - 1e-4) * (double)i / 99.0);
  const float decay = expf(-0.1f);
  float coh = 1.0f;

  dim3 blk(512);
  dim3 g8(256);                    // all 8-phase GEMMs: 256 blocks = 1/CU
  dim3 g7(F / 128, Nn / 64);       // (4,128) = 512 blocks, 64x128 tiles

  for (int j = 0; j < 50; j++) {
    int t = 49 - j;
    // G1 (8-phase 128x256): qf = relu(xbf @ Wq + bq)
    mfma_gemm_8ph_128x256<1, 0><<<g8, blk, 0, stream>>>(
        xbf, xbf, F, F, F, F, Wq_t, bq, qf, H,
        nullptr, nullptr, nullptr, nullptr);
    // G2 (8-phase 256^2): h0 = relu(qf@W01+b01), h1 = tanh(qf@W11+b11)
    mfma_gemm2_8ph<<<g8, blk, 0, stream>>>(qf, WA_t, b01, b11, h0, h1);
    // G4/G5 (8-phase 128x256, z-pair): d0 = h0@W02+b02 ; d1 = h1@W12+b12
    mfma_gemm_8ph_128x256<0, 1><<<g8, blk, 0, stream>>>(
        h0, h0, H, H, H, H, W02_t, b02, d0, F,
        h1, W12_t, b12, d1);
    // G6 (8-phase 128x256, A-split): qf = gelu([d0|d1] @ Wi1 + bi1)
    mfma_gemm_8ph_128x256<3, 0><<<g8, blk, 0, stream>>>(
        d0, d1, F, F, F, 2 * F, Wi1_t, bi1, qf, H,
        nullptr, nullptr, nullptr, nullptr);

    float schedt = sched[t];
    float alphaf = fmaxf(1.0f - schedt, 1e-8f);
    float one_m_alpha = 1.0f - alphaf;
    float sqrt_1ma = sqrtf(fmaxf(one_m_alpha, 1e-8f));
    float c1 = one_m_alpha / sqrt_1ma;
    float sqa = sqrtf(alphaf);
    float sigma = 0.0f;
    if (t > 0) {
      float ap = 1.0f - sched[t - 1];
      sigma = sqrtf(fmaxf((1.0f - ap) / one_m_alpha * (1.0f - alphaf / ap), 0.0f));
    }
    uint32_t kt0, kt1; tf2x32(0u, 1u, 0u, (uint32_t)t, kt0, kt1);
    // G7 fused: itf = qf @ Wi2 + bi2  +  DDPM update of x/xbf
    mfma_gemm_update<<<g7, blk, 0, stream>>>(
        qf, Wi2_t, bi2, d0, d1, x, xbf, a_amp, b_amp, ph, coh, c1, sqa, sigma,
        (t > 0) ? 1 : 0, kt0, kt1);
    coh *= decay;
  }

  uint32_t ku0, ku1; tf2x32(0u, 1u, 0u, 99999u, ku0, ku1);
  final_kernel<<<(nElem + 255) / 256, 256, 0, stream>>>(
      x, real, (float*)d_out, a_amp, b_amp, ku0, ku1, nElem);
}